// Round 1
// 881.447 us; speedup vs baseline: 1.1196x; 1.1196x over previous
//
#include <hip/hip_runtime.h>

#define POP   128
#define BATCH 256
#define DIN   1024
#define DOUT  1024

#define BM 128
#define BN 128
#define BK 32
#define NKT (DIN / BK)
#define LDS_K (BK + 8)   // bf16 elems; +8 pad: 80B row stride -> free 2-way alias, 16B aligned

typedef __attribute__((ext_vector_type(8))) short  short8v;
typedef __attribute__((ext_vector_type(4))) short  short4v;
typedef __attribute__((ext_vector_type(4))) float  float4v;

// fp32 -> bf16 round-to-nearest-even (inputs are finite Gaussians; no NaN path)
static __device__ __forceinline__ short f2bf(float f) {
    unsigned u = __builtin_bit_cast(unsigned, f);
    u += 0x7fffu + ((u >> 16) & 1u);
    return (short)(u >> 16);
}

__global__ __launch_bounds__(256, 3)
void pop_linear_kernel(const float* __restrict__ x,
                       const float* __restrict__ w,
                       const float* __restrict__ bias,
                       float* __restrict__ out) {
    // double-buffered bf16 tiles: 2 * (128*40 + 128*40) * 2B = 40 KB -> 4 blocks/CU by LDS
    __shared__ short As[2][BM * LDS_K];
    __shared__ short Bs[2][BN * LDS_K];

    const int bid = blockIdx.x;
    // p slow, m_tile middle (stride 8 -> same XCD pair shares W tile), n_tile fast
    const int p      = bid >> 4;
    const int m_tile = (bid >> 3) & 1;
    const int n_tile = bid & 7;

    const int tid    = threadIdx.x;
    const int lane   = tid & 63;
    const int wave   = tid >> 6;   // 0..3
    const int wm     = wave >> 1;  // 0..1  (row half)
    const int wn     = wave & 1;   // 0..1  (col half)
    const int lane15 = lane & 15;
    const int quad   = lane >> 4;  // 0..3

    const int m_base = m_tile * BM;
    const int n_base = n_tile * BN;

    // staging: 256 threads load 128 rows x 32 k-cols (float4 each), 4 passes
    const int srow = tid >> 3;        // 0..31
    const int scol = (tid & 7) * 4;   // 0,4,...,28

    const float* Ag = x + (size_t)(m_base + srow) * (POP * DIN) + (size_t)p * DIN + scol;
    const float* Bg = w + (size_t)p * ((size_t)DOUT * DIN) + (size_t)(n_base + srow) * DIN + scol;

    float4v acc[4][4];
    #pragma unroll
    for (int i = 0; i < 4; ++i)
        #pragma unroll
        for (int j = 0; j < 4; ++j)
            acc[i][j] = (float4v){0.f, 0.f, 0.f, 0.f};

    // ---- prologue: stage tile 0 into buffer 0 ----
    float4v av[4], bv[4];
    #pragma unroll
    for (int pass = 0; pass < 4; ++pass) {
        av[pass] = *(const float4v*)(Ag + (size_t)(pass * 32) * (POP * DIN));
        bv[pass] = *(const float4v*)(Bg + (size_t)(pass * 32) * DIN);
    }
    #pragma unroll
    for (int pass = 0; pass < 4; ++pass) {
        short4v a4, b4;
        #pragma unroll
        for (int e = 0; e < 4; ++e) {
            a4[e] = f2bf(av[pass][e]);
            b4[e] = f2bf(bv[pass][e]);
        }
        *(short4v*)&As[0][(pass * 32 + srow) * LDS_K + scol] = a4;
        *(short4v*)&Bs[0][(pass * 32 + srow) * LDS_K + scol] = b4;
    }
    __syncthreads();

    // ---- main loop: single barrier per K-step, 1-deep register prefetch ----
    // iter kt: loads for kt+1 fly across ds_read+MFMA of kt; convert+write land in
    // buf[cur^1]; the single end barrier both publishes those writes (for kt+1's
    // reads) and proves all waves finished kt-1's reads of buf[cur^1].
    for (int kt = 0; kt < NKT; ++kt) {
        const int cur  = kt & 1;
        const bool more = (kt + 1 < NKT);

        if (more) {
            const int k0 = (kt + 1) * BK;
            #pragma unroll
            for (int pass = 0; pass < 4; ++pass) {
                av[pass] = *(const float4v*)(Ag + (size_t)(pass * 32) * (POP * DIN) + k0);
                bv[pass] = *(const float4v*)(Bg + (size_t)(pass * 32) * DIN + k0);
            }
        }

        // fragments: A[m = lane&15][k = quad*8+j], B mirrors with n = lane&15
        short8v af[4], bf[4];
        #pragma unroll
        for (int i = 0; i < 4; ++i) {
            af[i] = *(const short8v*)&As[cur][(wm * 64 + i * 16 + lane15) * LDS_K + quad * 8];
            bf[i] = *(const short8v*)&Bs[cur][(wn * 64 + i * 16 + lane15) * LDS_K + quad * 8];
        }

        #pragma unroll
        for (int i = 0; i < 4; ++i)
            #pragma unroll
            for (int j = 0; j < 4; ++j)
                acc[i][j] = __builtin_amdgcn_mfma_f32_16x16x32_bf16(af[i], bf[j], acc[i][j], 0, 0, 0);

        if (more) {
            #pragma unroll
            for (int pass = 0; pass < 4; ++pass) {
                short4v a4, b4;
                #pragma unroll
                for (int e = 0; e < 4; ++e) {
                    a4[e] = f2bf(av[pass][e]);
                    b4[e] = f2bf(bv[pass][e]);
                }
                *(short4v*)&As[cur ^ 1][(pass * 32 + srow) * LDS_K + scol] = a4;
                *(short4v*)&Bs[cur ^ 1][(pass * 32 + srow) * LDS_K + scol] = b4;
            }
        }
        __syncthreads();
    }

    // epilogue: C/D layout m = quad*4 + reg, n = lane&15
    const float* bp = bias + (size_t)p * DOUT;
    float bj[4];
    #pragma unroll
    for (int j = 0; j < 4; ++j)
        bj[j] = bp[n_base + wn * 64 + j * 16 + lane15];

    #pragma unroll
    for (int i = 0; i < 4; ++i) {
        #pragma unroll
        for (int r = 0; r < 4; ++r) {
            const int m = m_base + wm * 64 + i * 16 + quad * 4 + r;
            float* orow = out + (size_t)m * (POP * DOUT) + (size_t)p * DOUT;
            #pragma unroll
            for (int j = 0; j < 4; ++j) {
                const int n = n_base + wn * 64 + j * 16 + lane15;
                orow[n] = acc[i][j][r] + bj[j];
            }
        }
    }
}

extern "C" void kernel_launch(void* const* d_in, const int* in_sizes, int n_in,
                              void* d_out, int out_size, void* d_ws, size_t ws_size,
                              hipStream_t stream) {
    const float* x    = (const float*)d_in[0];
    const float* w    = (const float*)d_in[1];
    const float* bias = (const float*)d_in[2];
    float* out        = (float*)d_out;

    const int grid = POP * (BATCH / BM) * (DOUT / BN);  // 128 * 2 * 8 = 2048
    pop_linear_kernel<<<grid, 256, 0, stream>>>(x, w, bias, out);
}